// Round 1
// baseline (3115.022 us; speedup 1.0000x reference)
//
#include <hip/hip_runtime.h>
#include <hip/hip_cooperative_groups.h>

namespace cg = cooperative_groups;

static constexpr int   BATCH = 131072;
static constexpr int   TS    = 30;
static constexpr int   DD    = 10;
static constexpr int   HH    = 20;
static constexpr float EPSV  = 1e-5f;
static constexpr float INV_B = 1.0f / (float)BATCH;

static constexpr int NBLK = 256;   // 1 block/CU guaranteed co-resident
static constexpr int NTHR = 256;
static constexpr int RPT  = 2;     // rows per thread: 131072 / (256*256)
static constexpr int TT   = NBLK * NTHR;

template <int CTRL>
__device__ __forceinline__ float dpp_add(float v) {
    int x = __builtin_amdgcn_update_dpp(0, __float_as_int(v), CTRL, 0xF, 0xF, true);
    return v + __int_as_float(x);
}

// Sum within each 16-lane row; lane 15 (+16k) holds the row total.
__device__ __forceinline__ float rowsum16(float v) {
    v = dpp_add<0x111>(v);  // row_shr:1
    v = dpp_add<0x112>(v);  // row_shr:2
    v = dpp_add<0x114>(v);  // row_shr:4
    v = dpp_add<0x118>(v);  // row_shr:8
    return v;
}

// Block-reduce 40 per-thread values, then one atomicAdd per feature per block.
__device__ __forceinline__ void reduce40(const float (&sv)[40], float* __restrict__ slot,
                                         float* __restrict__ lred, int tid) {
    float r[40];
#pragma unroll
    for (int i = 0; i < 40; ++i) r[i] = rowsum16(sv[i]);
    if ((tid & 15) == 15) {
        const int s16 = tid >> 4;  // 0..15
#pragma unroll
        for (int i = 0; i < 40; ++i) lred[s16 * 40 + i] = r[i];
    }
    __syncthreads();
    if (tid < 40) {
        float acc = 0.0f;
#pragma unroll
        for (int k = 0; k < 16; ++k) acc += lred[k * 40 + tid];
        atomicAdd(&slot[tid], acc);
    }
}

// From accumulated sum/sumsq, produce affine params: y = v*A + C  (A=g*rsqrt, C=b-mu*A)
__device__ __forceinline__ void bn_params(float* __restrict__ slot,
                                          const float* __restrict__ gam,
                                          const float* __restrict__ bet,
                                          float* __restrict__ sA, float* __restrict__ sC,
                                          int tid) {
    if (tid < 20) {
        float s  = __hip_atomic_load(&slot[tid],      __ATOMIC_RELAXED, __HIP_MEMORY_SCOPE_AGENT);
        float ss = __hip_atomic_load(&slot[tid + 20], __ATOMIC_RELAXED, __HIP_MEMORY_SCOPE_AGENT);
        float mu  = s * INV_B;
        float var = fmaf(-mu, mu, ss * INV_B);
        float a   = gam[tid] * rsqrtf(var + EPSV);
        sA[tid] = a;
        sC[tid] = fmaf(-mu, a, bet[tid]);
    }
    __syncthreads();
}

__global__ void __launch_bounds__(NTHR, 1)
rnn_bn_kernel(const float* __restrict__ x,
              const float* __restrict__ g0, const float* __restrict__ be0,
              const float* __restrict__ W1, const float* __restrict__ b1,
              const float* __restrict__ g1, const float* __restrict__ be1,
              const float* __restrict__ W2, const float* __restrict__ b2,
              const float* __restrict__ g2, const float* __restrict__ be2,
              const float* __restrict__ W3, const float* __restrict__ b3,
              float* __restrict__ out, float* __restrict__ red)
{
    __shared__ float lred[16 * 40];
    __shared__ float sA[20], sC[20];

    cg::grid_group grid = cg::this_grid();
    const int tid = threadIdx.x;
    const int gt  = blockIdx.x * NTHR + tid;

    float prev[RPT][DD];
#pragma unroll
    for (int r = 0; r < RPT; ++r)
#pragma unroll
        for (int d = 0; d < DD; ++d) prev[r][d] = 0.0f;

    for (int t = 0; t < TS; ++t) {
        // ---- load x_t (both rows)
        float xt[RPT][DD];
#pragma unroll
        for (int r = 0; r < RPT; ++r) {
            const float* px = x + ((size_t)(gt + r * TT) * TS + t) * DD;
#pragma unroll
            for (int d = 0; d < DD; ++d) xt[r][d] = px[d];
        }

        // ---- phase A: stats of concat(x_t, prev) -> BN0 accumulators
        {
            float sv[40];
#pragma unroll
            for (int f = 0; f < DD; ++f) {
                float a = xt[0][f],  b = xt[1][f];
                float c = prev[0][f], d = prev[1][f];
                sv[f]      = a + b;
                sv[20 + f] = fmaf(a, a, b * b);
                sv[10 + f] = c + d;
                sv[30 + f] = fmaf(c, c, d * d);
            }
            reduce40(sv, red + (size_t)(t * 3 + 0) * 64, lred, tid);
        }
        grid.sync();

        // ---- phase B: BN0 -> h0n, z1 = W1 h0n + b1, stats(z1)
        bn_params(red + (size_t)(t * 3 + 0) * 64, g0 + t * 2 * DD, be0 + t * 2 * DD, sA, sC, tid);
        float A[20], Cc[20];
#pragma unroll
        for (int f = 0; f < 20; ++f) { A[f] = sA[f]; Cc[f] = sC[f]; }

        float h[RPT][HH];
#pragma unroll
        for (int r = 0; r < RPT; ++r) {
#pragma unroll
            for (int f = 0; f < DD; ++f) h[r][f]      = fmaf(xt[r][f],   A[f],      Cc[f]);
#pragma unroll
            for (int f = 0; f < DD; ++f) h[r][DD + f] = fmaf(prev[r][f], A[DD + f], Cc[DD + f]);
        }

        float z[RPT][HH];
        {
            const float* Wt = W1 + (size_t)t * HH * (2 * DD);
            const float* bt = b1 + t * HH;
#pragma unroll
            for (int j = 0; j < HH; ++j) {
                float a0 = bt[j], a1 = bt[j];
#pragma unroll
                for (int k = 0; k < 2 * DD; ++k) {
                    float w = Wt[j * (2 * DD) + k];
                    a0 = fmaf(w, h[0][k], a0);
                    a1 = fmaf(w, h[1][k], a1);
                }
                z[0][j] = a0; z[1][j] = a1;
            }
        }
        {
            float sv[40];
#pragma unroll
            for (int j = 0; j < HH; ++j) {
                float a = z[0][j], b = z[1][j];
                sv[j] = a + b; sv[20 + j] = fmaf(a, a, b * b);
            }
            reduce40(sv, red + (size_t)(t * 3 + 1) * 64, lred, tid);
        }
        grid.sync();

        // ---- phase C: BN1+relu -> h1, z2 = W2 h1 + b2, stats(z2)
        bn_params(red + (size_t)(t * 3 + 1) * 64, g1 + t * HH, be1 + t * HH, sA, sC, tid);
#pragma unroll
        for (int f = 0; f < 20; ++f) { A[f] = sA[f]; Cc[f] = sC[f]; }
#pragma unroll
        for (int r = 0; r < RPT; ++r)
#pragma unroll
            for (int j = 0; j < HH; ++j)
                h[r][j] = fmaxf(fmaf(z[r][j], A[j], Cc[j]), 0.0f);
        {
            const float* Wt = W2 + (size_t)t * HH * HH;
            const float* bt = b2 + t * HH;
#pragma unroll
            for (int j = 0; j < HH; ++j) {
                float a0 = bt[j], a1 = bt[j];
#pragma unroll
                for (int k = 0; k < HH; ++k) {
                    float w = Wt[j * HH + k];
                    a0 = fmaf(w, h[0][k], a0);
                    a1 = fmaf(w, h[1][k], a1);
                }
                z[0][j] = a0; z[1][j] = a1;
            }
        }
        {
            float sv[40];
#pragma unroll
            for (int j = 0; j < HH; ++j) {
                float a = z[0][j], b = z[1][j];
                sv[j] = a + b; sv[20 + j] = fmaf(a, a, b * b);
            }
            reduce40(sv, red + (size_t)(t * 3 + 2) * 64, lred, tid);
        }
        grid.sync();

        // ---- phase D: BN2+relu -> h2, out = W3 h2 + b3, prev = out
        bn_params(red + (size_t)(t * 3 + 2) * 64, g2 + t * HH, be2 + t * HH, sA, sC, tid);
#pragma unroll
        for (int f = 0; f < 20; ++f) { A[f] = sA[f]; Cc[f] = sC[f]; }
#pragma unroll
        for (int r = 0; r < RPT; ++r)
#pragma unroll
            for (int j = 0; j < HH; ++j)
                h[r][j] = fmaxf(fmaf(z[r][j], A[j], Cc[j]), 0.0f);
        {
            const float* Wt = W3 + (size_t)t * DD * HH;
            const float* bt = b3 + t * DD;
#pragma unroll
            for (int r = 0; r < RPT; ++r) {
                float* po = out + ((size_t)(gt + r * TT) * TS + t) * DD;
#pragma unroll
                for (int d = 0; d < DD; ++d) {
                    float a = bt[d];
#pragma unroll
                    for (int j = 0; j < HH; ++j)
                        a = fmaf(Wt[d * HH + j], h[r][j], a);
                    po[d] = a;
                    prev[r][d] = a;
                }
            }
        }
    }
}

extern "C" void kernel_launch(void* const* d_in, const int* in_sizes, int n_in,
                              void* d_out, int out_size, void* d_ws, size_t ws_size,
                              hipStream_t stream) {
    const float* x   = (const float*)d_in[0];
    const float* g0  = (const float*)d_in[1];
    const float* be0 = (const float*)d_in[2];
    const float* W1  = (const float*)d_in[3];
    const float* b1  = (const float*)d_in[4];
    const float* g1  = (const float*)d_in[5];
    const float* be1 = (const float*)d_in[6];
    const float* W2  = (const float*)d_in[7];
    const float* b2  = (const float*)d_in[8];
    const float* g2  = (const float*)d_in[9];
    const float* be2 = (const float*)d_in[10];
    const float* W3  = (const float*)d_in[11];
    const float* b3  = (const float*)d_in[12];
    float* out = (float*)d_out;
    float* red = (float*)d_ws;

    // Re-zero stat accumulators every replay (graph-captured).
    hipMemsetAsync(d_ws, 0, (size_t)(TS * 3 * 64) * sizeof(float), stream);

    void* args[] = { &x, &g0, &be0, &W1, &b1, &g1, &be1, &W2, &b2, &g2, &be2,
                     &W3, &b3, &out, &red };
    hipLaunchCooperativeKernel((const void*)rnn_bn_kernel, dim3(NBLK), dim3(NTHR),
                               args, 0, stream);
}

// Round 2
// 2155.146 us; speedup vs baseline: 1.4454x; 1.4454x over previous
//
#include <hip/hip_runtime.h>

static constexpr int   BATCH = 131072;
static constexpr int   TS    = 30;
static constexpr int   DD    = 10;
static constexpr int   HH    = 20;
static constexpr float EPSV  = 1e-5f;
static constexpr float INV_B = 1.0f / (float)BATCH;

static constexpr int NBLK = 256;   // 1 block/CU, co-resident via cooperative launch
static constexpr int NTHR = 256;
static constexpr int RPT  = 2;     // rows per thread: 131072 / (256*256)
static constexpr int TT   = NBLK * NTHR;
static constexpr int NPH  = TS * 3;   // 90 barrier phases

template <int CTRL>
__device__ __forceinline__ float dpp_add(float v) {
    int x = __builtin_amdgcn_update_dpp(0, __float_as_int(v), CTRL, 0xF, 0xF, true);
    return v + __int_as_float(x);
}

// Sum within each 16-lane row; lane 15 (+16k) holds the row total.
__device__ __forceinline__ float rowsum16(float v) {
    v = dpp_add<0x111>(v);  // row_shr:1
    v = dpp_add<0x112>(v);  // row_shr:2
    v = dpp_add<0x114>(v);  // row_shr:4
    v = dpp_add<0x118>(v);  // row_shr:8
    return v;
}

// Block-reduce 40 per-thread values, then one atomicAdd per feature per block.
__device__ __forceinline__ void reduce40(const float (&sv)[40], float* __restrict__ slot,
                                         float* __restrict__ lred, int tid) {
    float r[40];
#pragma unroll
    for (int i = 0; i < 40; ++i) r[i] = rowsum16(sv[i]);
    if ((tid & 15) == 15) {
        const int s16 = tid >> 4;  // 0..15
#pragma unroll
        for (int i = 0; i < 40; ++i) lred[s16 * 40 + i] = r[i];
    }
    __syncthreads();
    if (tid < 40) {
        float acc = 0.0f;
#pragma unroll
        for (int k = 0; k < 16; ++k) acc += lred[k * 40 + tid];
        atomicAdd(&slot[tid], acc);
    }
}

// Hand-rolled grid barrier on a phase-unique counter (64B-padded).
// Blocks may run at most one phase ahead; all data slots are phase-unique.
__device__ __forceinline__ void gbar(unsigned* __restrict__ c, int tid) {
    __syncthreads();   // all stat atomics in this block issued & drained (vmcnt(0))
    if (tid == 0) {
        __hip_atomic_fetch_add(c, 1u, __ATOMIC_RELEASE, __HIP_MEMORY_SCOPE_AGENT);
        while (__hip_atomic_load(c, __ATOMIC_ACQUIRE, __HIP_MEMORY_SCOPE_AGENT) < (unsigned)NBLK)
            __builtin_amdgcn_s_sleep(1);
    }
    __syncthreads();
}

// From accumulated sum/sumsq, produce affine params: y = v*A + C  (A=g*rsqrt, C=b-mu*A)
__device__ __forceinline__ void bn_params(float* __restrict__ slot,
                                          const float* __restrict__ gam,
                                          const float* __restrict__ bet,
                                          float* __restrict__ sA, float* __restrict__ sC,
                                          int tid) {
    if (tid < 20) {
        float s  = __hip_atomic_load(&slot[tid],      __ATOMIC_RELAXED, __HIP_MEMORY_SCOPE_AGENT);
        float ss = __hip_atomic_load(&slot[tid + 20], __ATOMIC_RELAXED, __HIP_MEMORY_SCOPE_AGENT);
        float mu  = s * INV_B;
        float var = fmaf(-mu, mu, ss * INV_B);
        float a   = gam[tid] * rsqrtf(var + EPSV);
        sA[tid] = a;
        sC[tid] = fmaf(-mu, a, bet[tid]);
    }
    __syncthreads();
}

__global__ void __launch_bounds__(NTHR, 1)
rnn_bn_kernel(const float* __restrict__ x,
              const float* __restrict__ g0, const float* __restrict__ be0,
              const float* __restrict__ W1, const float* __restrict__ b1,
              const float* __restrict__ g1, const float* __restrict__ be1,
              const float* __restrict__ W2, const float* __restrict__ b2,
              const float* __restrict__ g2, const float* __restrict__ be2,
              const float* __restrict__ W3, const float* __restrict__ b3,
              float* __restrict__ out, float* __restrict__ red,
              unsigned* __restrict__ ctr)
{
    __shared__ float lred[16 * 40];
    __shared__ float sA[20], sC[20];

    const int tid = threadIdx.x;
    const int gt  = blockIdx.x * NTHR + tid;

    float prev[RPT][DD];
#pragma unroll
    for (int r = 0; r < RPT; ++r)
#pragma unroll
        for (int d = 0; d < DD; ++d) prev[r][d] = 0.0f;

    // preload x_0
    float xt[RPT][DD];
#pragma unroll
    for (int r = 0; r < RPT; ++r) {
        const float* px = x + ((size_t)(gt + r * TT) * TS + 0) * DD;
#pragma unroll
        for (int d = 0; d < DD; ++d) xt[r][d] = px[d];
    }

    for (int t = 0; t < TS; ++t) {
        // ---- phase A: stats of concat(x_t, prev) -> BN0 accumulators
        {
            float sv[40];
#pragma unroll
            for (int f = 0; f < DD; ++f) {
                float a = xt[0][f],  b = xt[1][f];
                float c = prev[0][f], d = prev[1][f];
                sv[f]      = a + b;
                sv[20 + f] = fmaf(a, a, b * b);
                sv[10 + f] = c + d;
                sv[30 + f] = fmaf(c, c, d * d);
            }
            reduce40(sv, red + (size_t)(t * 3 + 0) * 64, lred, tid);
        }
        gbar(ctr + (size_t)(t * 3 + 0) * 16, tid);

        // ---- phase B: BN0 -> h0n, z1 = W1 h0n + b1, stats(z1)
        bn_params(red + (size_t)(t * 3 + 0) * 64, g0 + t * 2 * DD, be0 + t * 2 * DD, sA, sC, tid);
        float A[20], Cc[20];
#pragma unroll
        for (int f = 0; f < 20; ++f) { A[f] = sA[f]; Cc[f] = sC[f]; }

        float h[RPT][HH];
#pragma unroll
        for (int r = 0; r < RPT; ++r) {
#pragma unroll
            for (int f = 0; f < DD; ++f) h[r][f]      = fmaf(xt[r][f],   A[f],      Cc[f]);
#pragma unroll
            for (int f = 0; f < DD; ++f) h[r][DD + f] = fmaf(prev[r][f], A[DD + f], Cc[DD + f]);
        }

        float z[RPT][HH];
        {
            const float* Wt = W1 + (size_t)t * HH * (2 * DD);
            const float* bt = b1 + t * HH;
#pragma unroll
            for (int j = 0; j < HH; ++j) {
                float a0 = bt[j], a1 = bt[j];
#pragma unroll
                for (int k = 0; k < 2 * DD; ++k) {
                    float w = Wt[j * (2 * DD) + k];
                    a0 = fmaf(w, h[0][k], a0);
                    a1 = fmaf(w, h[1][k], a1);
                }
                z[0][j] = a0; z[1][j] = a1;
            }
        }
        {
            float sv[40];
#pragma unroll
            for (int j = 0; j < HH; ++j) {
                float a = z[0][j], b = z[1][j];
                sv[j] = a + b; sv[20 + j] = fmaf(a, a, b * b);
            }
            reduce40(sv, red + (size_t)(t * 3 + 1) * 64, lred, tid);
        }
        gbar(ctr + (size_t)(t * 3 + 1) * 16, tid);

        // ---- phase C: BN1+relu -> h1, z2 = W2 h1 + b2, stats(z2)
        bn_params(red + (size_t)(t * 3 + 1) * 64, g1 + t * HH, be1 + t * HH, sA, sC, tid);
#pragma unroll
        for (int f = 0; f < 20; ++f) { A[f] = sA[f]; Cc[f] = sC[f]; }
#pragma unroll
        for (int r = 0; r < RPT; ++r)
#pragma unroll
            for (int j = 0; j < HH; ++j)
                h[r][j] = fmaxf(fmaf(z[r][j], A[j], Cc[j]), 0.0f);
        {
            const float* Wt = W2 + (size_t)t * HH * HH;
            const float* bt = b2 + t * HH;
#pragma unroll
            for (int j = 0; j < HH; ++j) {
                float a0 = bt[j], a1 = bt[j];
#pragma unroll
                for (int k = 0; k < HH; ++k) {
                    float w = Wt[j * HH + k];
                    a0 = fmaf(w, h[0][k], a0);
                    a1 = fmaf(w, h[1][k], a1);
                }
                z[0][j] = a0; z[1][j] = a1;
            }
        }
        {
            float sv[40];
#pragma unroll
            for (int j = 0; j < HH; ++j) {
                float a = z[0][j], b = z[1][j];
                sv[j] = a + b; sv[20 + j] = fmaf(a, a, b * b);
            }
            reduce40(sv, red + (size_t)(t * 3 + 2) * 64, lred, tid);
        }

        // prefetch x_{t+1}; HBM latency hides under the barrier wait
        float xn[RPT][DD];
        if (t + 1 < TS) {
#pragma unroll
            for (int r = 0; r < RPT; ++r) {
                const float* px = x + ((size_t)(gt + r * TT) * TS + (t + 1)) * DD;
#pragma unroll
                for (int d = 0; d < DD; ++d) xn[r][d] = px[d];
            }
        }
        gbar(ctr + (size_t)(t * 3 + 2) * 16, tid);

        // ---- phase D: BN2+relu -> h2, out = W3 h2 + b3, prev = out
        bn_params(red + (size_t)(t * 3 + 2) * 64, g2 + t * HH, be2 + t * HH, sA, sC, tid);
#pragma unroll
        for (int f = 0; f < 20; ++f) { A[f] = sA[f]; Cc[f] = sC[f]; }
#pragma unroll
        for (int r = 0; r < RPT; ++r)
#pragma unroll
            for (int j = 0; j < HH; ++j)
                h[r][j] = fmaxf(fmaf(z[r][j], A[j], Cc[j]), 0.0f);
        {
            const float* Wt = W3 + (size_t)t * DD * HH;
            const float* bt = b3 + t * DD;
#pragma unroll
            for (int r = 0; r < RPT; ++r) {
                float* po = out + ((size_t)(gt + r * TT) * TS + t) * DD;
#pragma unroll
                for (int d = 0; d < DD; ++d) {
                    float a = bt[d];
#pragma unroll
                    for (int j = 0; j < HH; ++j)
                        a = fmaf(Wt[d * HH + j], h[r][j], a);
                    po[d] = a;
                    prev[r][d] = a;
                }
            }
        }
        if (t + 1 < TS) {
#pragma unroll
            for (int r = 0; r < RPT; ++r)
#pragma unroll
                for (int d = 0; d < DD; ++d) xt[r][d] = xn[r][d];
        }
    }
}

extern "C" void kernel_launch(void* const* d_in, const int* in_sizes, int n_in,
                              void* d_out, int out_size, void* d_ws, size_t ws_size,
                              hipStream_t stream) {
    const float* x   = (const float*)d_in[0];
    const float* g0  = (const float*)d_in[1];
    const float* be0 = (const float*)d_in[2];
    const float* W1  = (const float*)d_in[3];
    const float* b1  = (const float*)d_in[4];
    const float* g1  = (const float*)d_in[5];
    const float* be1 = (const float*)d_in[6];
    const float* W2  = (const float*)d_in[7];
    const float* b2  = (const float*)d_in[8];
    const float* g2  = (const float*)d_in[9];
    const float* be2 = (const float*)d_in[10];
    const float* W3  = (const float*)d_in[11];
    const float* b3  = (const float*)d_in[12];
    float* out = (float*)d_out;

    float*    red = (float*)d_ws;                                  // [NPH][64] stats
    unsigned* ctr = (unsigned*)((char*)d_ws + (size_t)NPH * 64 * 4);  // [NPH][16] barriers

    // Re-zero stat accumulators + barrier counters every replay (graph-captured).
    hipMemsetAsync(d_ws, 0, (size_t)NPH * 64 * 4 + (size_t)NPH * 16 * 4, stream);

    void* args[] = { &x, &g0, &be0, &W1, &b1, &g1, &be1, &W2, &b2, &g2, &be2,
                     &W3, &b3, &out, &red, &ctr };
    hipLaunchCooperativeKernel((const void*)rnn_bn_kernel, dim3(NBLK), dim3(NTHR),
                               args, 0, stream);
}